// Round 3
// baseline (2057.156 us; speedup 1.0000x reference)
//
#include <hip/hip_runtime.h>

// KCenterSampler FPS — register-resident coordinates version.
// Each of the 8 segments gets one 1024-thread block; each thread owns
// 6 (+1 tail) of the 6272 points with coords/sq/distance all in VGPRs.
// Per step only the farthest point's 35 floats are re-read (L2 broadcast).
// Arithmetic is bit-identical to the verified round-1 kernel.

#define NPTS 6272
#define CDIM 35
#define BT   8
#define KSEL 128
#define THW  12544        // T*H*W
#define BLK  1024
#define NPMAIN 6          // round-robin points per thread
#define TAIL (NPTS - NPMAIN * BLK)   // 128 threads own one extra point

__global__ __launch_bounds__(BLK) void fps_kernel(const float* __restrict__ x,
                                                  const int* __restrict__ init_,
                                                  int* __restrict__ out_idx) {
  __shared__ float sq_s[NPTS];
  __shared__ float rv[16];
  __shared__ int   ri[16];
  __shared__ int   far_s;

  const int b   = blockIdx.x;
  const int tid = (int)threadIdx.x;
  const float* xg = x + (size_t)b * NPTS * CDIM;

  float xr[NPMAIN + 1][CDIM];   // register-resident coords
  float sqr[NPMAIN + 1];        // register-resident sq
  float df[NPMAIN + 1];         // register-resident running distance

  // ---- init: load coords, compute sq (strict sequential, contract off) ----
#pragma unroll
  for (int p = 0; p <= NPMAIN; ++p) {
    const bool act = (p < NPMAIN) || (tid < TAIL);
    if (act) {
      const int j = p * BLK + tid;            // round-robin global index
      const float* src = xg + (size_t)j * CDIM;
      float acc = 0.0f;
      {
#pragma clang fp contract(off)
#pragma unroll
        for (int c = 0; c < CDIM; ++c) {
          float v = src[c];
          xr[p][c] = v;
          acc = acc + v * v;
        }
      }
      sqr[p] = acc;
      sq_s[j] = acc;
      df[p] = 50000.0f;                       // FILL_DIST
    }
  }
  if (tid == 0) {
    int f = init_[b] % NPTS;
    if (f < 0) f += NPTS;                     // jnp.remainder semantics
    far_s = f;
    out_idx[b * KSEL] = f;
  }
  __syncthreads();
  int far = far_s;

  // ---- 127 sequential FPS steps, all operands in registers ----
  for (int step = 1; step < KSEL; ++step) {
    // farthest point's coords: same-address broadcast loads (L2-hit)
    float xf[CDIM];
#pragma unroll
    for (int c = 0; c < CDIM; ++c) xf[c] = xg[(size_t)far * CDIM + c];
    const float sqf = sq_s[far];              // LDS broadcast

    float best_v = -3.0f;
    int   best_i = 0x7fffffff;

#pragma unroll
    for (int p = 0; p <= NPMAIN; ++p) {
      const bool act = (p < NPMAIN) || (tid < TAIL);
      if (act) {
        const int j = p * BLK + tid;
        float dot = 0.0f;
#pragma unroll
        for (int c = 0; c < CDIM; ++c)
          dot = __builtin_fmaf(xf[c], xr[p][c], dot);   // k-sequential FMA (Eigen order)
        float d2;
        {
#pragma clang fp contract(off)
          d2 = (sqf + sqr[p]) - 2.0f * dot;             // exact reference formula order
        }
        d2 = fmaxf(d2, 0.0f);
        float d = __fsqrt_rn(d2);                       // correctly-rounded sqrt
        d = (j == far) ? -1.0f : d;                     // diagonal = -1
        float nd = fminf(d, df[p]);                     // f32 min-carry
        df[p] = nd;
        if (nd > best_v || (nd == best_v && j < best_i)) { best_v = nd; best_i = j; }
      }
    }

    // wave-level argmax (first-index tie-break)
#pragma unroll
    for (int off = 32; off > 0; off >>= 1) {
      float ov = __shfl_down(best_v, off);
      int   oi = __shfl_down(best_i, off);
      if (ov > best_v || (ov == best_v && oi < best_i)) { best_v = ov; best_i = oi; }
    }
    const int wid = tid >> 6, lane = tid & 63;
    if (lane == 0) { rv[wid] = best_v; ri[wid] = best_i; }
    __syncthreads();
    if (tid < 64) {
      best_v = (tid < 16) ? rv[tid] : -4.0f;
      best_i = (tid < 16) ? ri[tid] : 0x7fffffff;
#pragma unroll
      for (int off = 8; off > 0; off >>= 1) {
        float ov = __shfl_down(best_v, off);
        int   oi = __shfl_down(best_i, off);
        if (ov > best_v || (ov == best_v && oi < best_i)) { best_v = ov; best_i = oi; }
      }
      if (tid == 0) { far_s = best_i; out_idx[b * KSEL + step] = best_i; }
    }
    __syncthreads();
    far = far_s;
  }
}

// ---------------------------------------------------------------------------
// gather patches (first 32 channels) + write indices (as f32)
// ---------------------------------------------------------------------------
__global__ __launch_bounds__(256) void gather_kernel(const float* __restrict__ x,
                                                     const int* __restrict__ out_idx,
                                                     float* __restrict__ patches,
                                                     float* __restrict__ sidx) {
  const int b = blockIdx.x;          // 0..3
  const int m = (int)threadIdx.x;    // 0..255
  const int td = m >> 7;             // time segment 0/1
  const int i  = m & 127;
  const int li = out_idx[(b * 2 + td) * KSEL + i];
  const int gi = li + td * NPTS;     // + per-segment offset
  sidx[b * 256 + m] = (float)gi;
  const float* src = x + ((size_t)b * THW + gi) * CDIM;
  float* dst = patches + ((size_t)b * 256 + m) * 32;
#pragma unroll
  for (int c = 0; c < 32; ++c) dst[c] = src[c];   // first C-3 channels
}

extern "C" void kernel_launch(void* const* d_in, const int* in_sizes, int n_in,
                              void* d_out, int out_size, void* d_ws, size_t ws_size,
                              hipStream_t stream) {
  const float* x    = (const float*)d_in[0];
  const int*   init = (const int*)d_in[1];
  (void)in_sizes; (void)n_in; (void)out_size; (void)ws_size;

  int* idx = (int*)d_ws;                       // BT*KSEL ints of scratch

  float* patches = (float*)d_out;
  float* sidx    = patches + (size_t)4 * 256 * 32;

  hipLaunchKernelGGL(fps_kernel, dim3(BT), dim3(BLK), 0, stream, x, init, idx);
  hipLaunchKernelGGL(gather_kernel, dim3(4), dim3(256), 0, stream, x, idx, patches, sidx);
}

// Round 4
// 435.000 us; speedup vs baseline: 4.7291x; 4.7291x over previous
//
#include <hip/hip_runtime.h>

// KCenterSampler FPS — multi-CU-per-segment version.
// 8 segments × 16 blocks each (128 blocks, cooperatively launched).
// Each block owns 392 points, fully LDS-resident (coords channel-major,
// sq, running distance). Per FPS step: local distance update + block argmax,
// then a custom per-segment barrier via per-step global u64 slots
// (packed (monotone(dist), NPTS-j) keys, atomicMax-free: each block writes
// its own slot, 16 lanes spin until all nonzero, everyone reduces).
// Arithmetic bit-identical to the verified round-1 kernel (absmax 0).

#define NPTS 6272
#define CDIM 35
#define BT   8
#define KSEL 128
#define THW  12544
#define BPS  16                 // blocks per segment
#define PPB  (NPTS / BPS)       // 392 points per block
#define BLK  256
#define NB   (BT * BPS)         // 128 blocks total

__device__ __forceinline__ unsigned long long key_of(float v, int j) {
  unsigned int u = __float_as_uint(v);
  u = (u & 0x80000000u) ? ~u : (u | 0x80000000u);   // monotone float -> uint map
  return ((unsigned long long)u << 32) | (unsigned int)(NPTS - j); // low part nonzero
}
__device__ __forceinline__ unsigned long long kmax(unsigned long long a,
                                                   unsigned long long b) {
  return a > b ? a : b;
}

__global__ __launch_bounds__(BLK) void fps_kernel(const float* __restrict__ x,
                                                  const int* __restrict__ init_,
                                                  int* __restrict__ out_idx,
                                                  unsigned long long* __restrict__ slots) {
  __shared__ float xls[CDIM][PPB];     // owned coords, channel-major
  __shared__ float sqls[PPB];
  __shared__ float df[PPB];            // running distance (f32 carry)
  __shared__ float xf_s[CDIM];
  __shared__ unsigned long long wk[4];
  __shared__ unsigned long long keys16[BPS];

  const int bid = (int)blockIdx.x;
  const int b   = bid / BPS;           // segment 0..7
  const int sub = bid % BPS;           // sub-block within segment
  const int tid = (int)threadIdx.x;
  const int j0  = sub * PPB;           // first owned global point index
  const float* xg = x + (size_t)b * NPTS * CDIM;
  unsigned long long* seg_slots = slots + (size_t)b * KSEL * BPS;

  // ---- coalesced stage of owned panel into LDS (channel-major) ----
  {
    const float* src = xg + (size_t)j0 * CDIM;   // contiguous point-major region
    for (int t = tid; t < PPB * CDIM; t += BLK) {
      int lp = t / CDIM;
      int c  = t - lp * CDIM;
      xls[c][lp] = src[t];
    }
  }
  __syncthreads();

  // ---- sq for owned points: strict sequential, contract off ----
  for (int lp = tid; lp < PPB; lp += BLK) {
    float acc = 0.0f;
    {
#pragma clang fp contract(off)
#pragma unroll
      for (int c = 0; c < CDIM; ++c) { float v = xls[c][lp]; acc = acc + v * v; }
    }
    sqls[lp] = acc;
    df[lp] = 50000.0f;                 // FILL_DIST
  }

  int far;
  { int f = init_[b] % NPTS; if (f < 0) f += NPTS; far = f; }  // jnp.remainder
  if (sub == 0 && tid == 0) out_idx[b * KSEL] = far;
  __syncthreads();

  // ---- 127 sequential FPS steps ----
  for (int step = 1; step < KSEL; ++step) {
    // farthest point's coords: broadcast load (L2-hit)
    if (tid < CDIM) xf_s[tid] = xg[(size_t)far * CDIM + tid];
    __syncthreads();

    // sqf recomputed sequentially from identical f32 values -> bitwise equal
    float sqf;
    {
#pragma clang fp contract(off)
      float a = 0.0f;
#pragma unroll
      for (int c = 0; c < CDIM; ++c) { float v = xf_s[c]; a = a + v * v; }
      sqf = a;
    }

    unsigned long long bk = 0ull;
#pragma unroll
    for (int p = 0; p < 2; ++p) {
      const int lp = p * BLK + tid;
      if (lp < PPB) {
        float dot = 0.0f;
#pragma unroll
        for (int c = 0; c < CDIM; ++c)
          dot = __builtin_fmaf(xf_s[c], xls[c][lp], dot);  // k-sequential FMA
        float d2;
        {
#pragma clang fp contract(off)
          d2 = (sqf + sqls[lp]) - 2.0f * dot;              // reference formula order
        }
        d2 = fmaxf(d2, 0.0f);
        float d = __fsqrt_rn(d2);
        const int j = j0 + lp;
        d = (j == far) ? -1.0f : d;                        // diagonal = -1
        float nd = fminf(d, df[lp]);                       // f32 min-carry
        df[lp] = nd;
        bk = kmax(bk, key_of(nd, j));
      }
    }

    // wave-level max of packed keys (order = (val, first-index))
#pragma unroll
    for (int off = 32; off > 0; off >>= 1)
      bk = kmax(bk, __shfl_down(bk, off));
    if ((tid & 63) == 0) wk[tid >> 6] = bk;
    __syncthreads();

    if (tid == 0) {
      unsigned long long m = kmax(kmax(wk[0], wk[1]), kmax(wk[2], wk[3]));
      __hip_atomic_store(&seg_slots[step * BPS + sub], m,
                         __ATOMIC_RELEASE, __HIP_MEMORY_SCOPE_AGENT);
    }
    // 16 lanes spin on the 16 per-step slots (payload self-contained)
    if (tid < BPS) {
      unsigned long long k;
      do {
        k = __hip_atomic_load(&seg_slots[step * BPS + tid],
                              __ATOMIC_RELAXED, __HIP_MEMORY_SCOPE_AGENT);
      } while (k == 0ull);
      keys16[tid] = k;
    }
    __syncthreads();

    unsigned long long wkey = keys16[0];
#pragma unroll
    for (int t = 1; t < BPS; ++t) wkey = kmax(wkey, keys16[t]);
    far = NPTS - (int)(unsigned int)(wkey & 0xFFFFFFFFull);
    if (sub == 0 && tid == 0) out_idx[b * KSEL + step] = far;
    __syncthreads();   // protect xf_s / keys16 reuse next iteration
  }
}

// ---------------------------------------------------------------------------
// gather patches (first 32 channels) + write indices (as f32)
// ---------------------------------------------------------------------------
__global__ __launch_bounds__(256) void gather_kernel(const float* __restrict__ x,
                                                     const int* __restrict__ out_idx,
                                                     float* __restrict__ patches,
                                                     float* __restrict__ sidx) {
  const int b = (int)blockIdx.x;     // 0..3
  const int m = (int)threadIdx.x;    // 0..255
  const int td = m >> 7;             // time segment 0/1
  const int i  = m & 127;
  const int li = out_idx[(b * 2 + td) * KSEL + i];
  const int gi = li + td * NPTS;     // + per-segment offset
  sidx[b * 256 + m] = (float)gi;
  const float* src = x + ((size_t)b * THW + gi) * CDIM;
  float* dst = patches + ((size_t)b * 256 + m) * 32;
#pragma unroll
  for (int c = 0; c < 32; ++c) dst[c] = src[c];   // first C-3 channels
}

extern "C" void kernel_launch(void* const* d_in, const int* in_sizes, int n_in,
                              void* d_out, int out_size, void* d_ws, size_t ws_size,
                              hipStream_t stream) {
  const float* x    = (const float*)d_in[0];
  const int*   init = (const int*)d_in[1];
  (void)in_sizes; (void)n_in; (void)out_size; (void)ws_size;

  // workspace layout: slots [BT*KSEL*BPS u64] | idx [BT*KSEL int]
  unsigned long long* slots = (unsigned long long*)d_ws;
  const size_t slots_bytes = (size_t)BT * KSEL * BPS * sizeof(unsigned long long);
  int* idx = (int*)((char*)d_ws + slots_bytes);

  float* patches = (float*)d_out;
  float* sidx    = patches + (size_t)4 * 256 * 32;

  // zero the sync slots every launch (graph-replay safe, stream-ordered)
  hipMemsetAsync(d_ws, 0, slots_bytes, stream);

  void* kargs[] = { (void*)&x, (void*)&init, (void*)&idx, (void*)&slots };
  hipLaunchCooperativeKernel((const void*)fps_kernel, dim3(NB), dim3(BLK),
                             kargs, 0, stream);

  hipLaunchKernelGGL(gather_kernel, dim3(4), dim3(256), 0, stream,
                     x, idx, patches, sidx);
}

// Round 5
// 273.382 us; speedup vs baseline: 7.5248x; 1.5912x over previous
//
#include <hip/hip_runtime.h>

// KCenterSampler FPS — register-resident + lightweight cross-block sync.
// 8 segments × 16 blocks (128 blocks, cooperative). Each 256-thread block
// owns 392 points: coords (2×35 floats), sq, running distance all in VGPRs
// (static indices only — no scratch). Per step: pure-register distance
// update, wave shfl argmax, RELAXED agent-scope u64 key publish (payload
// self-contained), 16-lane spin on the 16 per-step slots, in-wave key max.
// Only 2 __syncthreads per step. Arithmetic bit-identical to the verified
// round-1/3 kernels (absmax 0).

#define NPTS 6272
#define CDIM 35
#define BT   8
#define KSEL 128
#define THW  12544
#define BPS  16                 // blocks per segment
#define PPB  (NPTS / BPS)       // 392 points per block
#define BLK  256
#define NB   (BT * BPS)         // 128 blocks
#define NPT  2                  // points per thread

__device__ __forceinline__ unsigned long long key_of(float v, int j) {
  unsigned int u = __float_as_uint(v);
  u = (u & 0x80000000u) ? ~u : (u | 0x80000000u);   // monotone float->uint
  return ((unsigned long long)u << 32) | (unsigned int)(NPTS - j); // low!=0
}
__device__ __forceinline__ unsigned long long kmax(unsigned long long a,
                                                   unsigned long long b) {
  return a > b ? a : b;
}

__global__ __launch_bounds__(BLK, 1) void fps_kernel(const float* __restrict__ x,
                                                     const int* __restrict__ init_,
                                                     int* __restrict__ out_idx,
                                                     unsigned long long* __restrict__ slots) {
  __shared__ unsigned long long wk[4];
  __shared__ int far_s;

  const int bid = (int)blockIdx.x;
  const int b   = bid / BPS;           // segment
  const int sub = bid % BPS;           // sub-block within segment
  const int tid = (int)threadIdx.x;
  const int j0  = sub * PPB;
  const float* xg = x + (size_t)b * NPTS * CDIM;
  unsigned long long* seg = slots + (size_t)b * KSEL * BPS;

  float xr[NPT][CDIM];                 // register-resident coords (static idx)
  float sqr[NPT], df[NPT];

  // ---- one-time load + sq (strict sequential, contract off) ----
#pragma unroll
  for (int p = 0; p < NPT; ++p) {
    const int lp = p * BLK + tid;
    if (lp < PPB) {
      const float* src = xg + (size_t)(j0 + lp) * CDIM;
      float acc = 0.0f;
      {
#pragma clang fp contract(off)
#pragma unroll
        for (int c = 0; c < CDIM; ++c) { float v = src[c]; xr[p][c] = v; acc = acc + v * v; }
      }
      sqr[p] = acc;
      df[p] = 50000.0f;                // FILL_DIST
    }
  }

  int far;
  { int f = init_[b] % NPTS; if (f < 0) f += NPTS; far = f; }   // jnp.remainder
  if (sub == 0 && tid == 0) out_idx[b * KSEL] = far;

  // ---- 127 sequential FPS steps ----
  for (int step = 1; step < KSEL; ++step) {
    // farthest point's coords: uniform-address broadcast load into registers
    const int fu = __builtin_amdgcn_readfirstlane(far);
    const float* fx = xg + (size_t)fu * CDIM;
    float xf[CDIM];
#pragma unroll
    for (int c = 0; c < CDIM; ++c) xf[c] = fx[c];

    // sqf recomputed sequentially from identical f32 values -> bitwise equal
    float sqf;
    {
#pragma clang fp contract(off)
      float a = 0.0f;
#pragma unroll
      for (int c = 0; c < CDIM; ++c) { float v = xf[c]; a = a + v * v; }
      sqf = a;
    }

    unsigned long long bk = 0ull;
#pragma unroll
    for (int p = 0; p < NPT; ++p) {
      const int lp = p * BLK + tid;
      if (lp < PPB) {
        float dot = 0.0f;
#pragma unroll
        for (int c = 0; c < CDIM; ++c)
          dot = __builtin_fmaf(xf[c], xr[p][c], dot);      // k-sequential FMA
        float d2;
        {
#pragma clang fp contract(off)
          d2 = (sqf + sqr[p]) - 2.0f * dot;                // reference order
        }
        d2 = fmaxf(d2, 0.0f);
        float d = __fsqrt_rn(d2);
        const int j = j0 + lp;
        d = (j == far) ? -1.0f : d;                        // diagonal = -1
        float nd = fminf(d, df[p]);                        // f32 min-carry
        df[p] = nd;
        bk = kmax(bk, key_of(nd, j));
      }
    }

    // wave-level max of packed keys (order = (value, first-index))
#pragma unroll
    for (int off = 32; off > 0; off >>= 1)
      bk = kmax(bk, __shfl_down(bk, off));
    if ((tid & 63) == 0) wk[tid >> 6] = bk;
    __syncthreads();                                       // barrier 1

    if (tid < BPS) {
      if (tid == 0) {
        unsigned long long m = kmax(kmax(wk[0], wk[1]), kmax(wk[2], wk[3]));
        // payload self-contained -> RELAXED is sufficient (no fence)
        __hip_atomic_store(&seg[step * BPS + sub], m,
                           __ATOMIC_RELAXED, __HIP_MEMORY_SCOPE_AGENT);
      }
      asm volatile("" ::: "memory");   // keep store ahead of the spin loop
      unsigned long long k;
      do {
        k = __hip_atomic_load(&seg[step * BPS + tid],
                              __ATOMIC_RELAXED, __HIP_MEMORY_SCOPE_AGENT);
      } while (k == 0ull);
      // in-wave max over the 16 polled keys (lanes 0..15)
#pragma unroll
      for (int off = 8; off > 0; off >>= 1)
        k = kmax(k, __shfl_down(k, off));
      if (tid == 0) {
        int f = NPTS - (int)(unsigned int)(k & 0xFFFFFFFFull);
        far_s = f;
        if (sub == 0) out_idx[b * KSEL + step] = f;
      }
    }
    __syncthreads();                                       // barrier 2
    far = far_s;
  }
}

// ---------------------------------------------------------------------------
// gather patches (first 32 channels) + write indices (as f32)
// ---------------------------------------------------------------------------
__global__ __launch_bounds__(256) void gather_kernel(const float* __restrict__ x,
                                                     const int* __restrict__ out_idx,
                                                     float* __restrict__ patches,
                                                     float* __restrict__ sidx) {
  const int b = (int)blockIdx.x;     // 0..3
  const int m = (int)threadIdx.x;    // 0..255
  const int td = m >> 7;             // time segment 0/1
  const int i  = m & 127;
  const int li = out_idx[(b * 2 + td) * KSEL + i];
  const int gi = li + td * NPTS;
  sidx[b * 256 + m] = (float)gi;
  const float* src = x + ((size_t)b * THW + gi) * CDIM;
  float* dst = patches + ((size_t)b * 256 + m) * 32;
#pragma unroll
  for (int c = 0; c < 32; ++c) dst[c] = src[c];   // first C-3 channels
}

extern "C" void kernel_launch(void* const* d_in, const int* in_sizes, int n_in,
                              void* d_out, int out_size, void* d_ws, size_t ws_size,
                              hipStream_t stream) {
  const float* x    = (const float*)d_in[0];
  const int*   init = (const int*)d_in[1];
  (void)in_sizes; (void)n_in; (void)out_size; (void)ws_size;

  unsigned long long* slots = (unsigned long long*)d_ws;
  const size_t slots_bytes = (size_t)BT * KSEL * BPS * sizeof(unsigned long long);
  int* idx = (int*)((char*)d_ws + slots_bytes);

  float* patches = (float*)d_out;
  float* sidx    = patches + (size_t)4 * 256 * 32;

  hipMemsetAsync(d_ws, 0, slots_bytes, stream);   // zero sync slots per launch

  void* kargs[] = { (void*)&x, (void*)&init, (void*)&idx, (void*)&slots };
  hipLaunchCooperativeKernel((const void*)fps_kernel, dim3(NB), dim3(BLK),
                             kargs, 0, stream);

  hipLaunchKernelGGL(gather_kernel, dim3(4), dim3(256), 0, stream,
                     x, idx, patches, sidx);
}